// Round 5
// baseline (217.375 us; speedup 1.0000x reference)
//
#include <hip/hip_runtime.h>
#include <math.h>

// SoftKConv, round 5.
// r4 post-mortem: softk LDS-pipe-bound (930 LDS-cyc/node measured = staging
// 470 + bpermutes 465). r5: (a) drop the LDS transpose epilogue — VALU
// epilogue re-gathers rows coalesced from global with SGPR (wave-uniform)
// bases; (b) fold -(sq_m+sq_c)/2 into the Gram via a 9th homogeneous-coord
// MFMA (hi/lo f16 split, d2 noise ~3e-5) + eps=1e-4 dist threshold -> no sq
// bpermutes, exact-zero diagonal; (c) zero LDS -> VGPR-only occupancy.

typedef __attribute__((ext_vector_type(2)))  _Float16 half2v;
typedef __attribute__((ext_vector_type(4)))  _Float16 half4v;
typedef __attribute__((ext_vector_type(8)))  _Float16 half8;
typedef __attribute__((ext_vector_type(16))) float    f32x16;

#define NK   32
#define DIM  128

// ---------------- Kernel 0: WT[n][k] = (f16) W[k][n] -----------------------
__global__ __launch_bounds__(256) void prep(const float* __restrict__ W,
                                            _Float16* __restrict__ WT) {
    int t  = blockIdx.x * 256 + threadIdx.x;   // 0..16383
    int nn = t >> 7, k = t & 127;
    WT[t] = (_Float16)W[k * 128 + nn];
}

// ---------------- Kernel 1: h = feat @ W -> f16, MFMA ----------------------
__global__ __launch_bounds__(256) void gemm128(
    const float* __restrict__ A, const _Float16* __restrict__ WT,
    _Float16* __restrict__ Hq, int n)
{
    const int wave = threadIdx.x >> 6;
    const int lane = threadIdx.x & 63;
    const int l31  = lane & 31;
    const int hf   = lane >> 5;

    const int row  = blockIdx.x * 128 + wave * 32 + l31;
    const int rowc = row < n ? row : n - 1;

    f32x16 acc[4];
#pragma unroll
    for (int t = 0; t < 4; ++t)
#pragma unroll
        for (int i = 0; i < 16; ++i) acc[t][i] = 0.0f;

    const float* ap = A + (size_t)rowc * 128 + 8 * hf;
#pragma unroll
    for (int s = 0; s < 8; ++s) {
        float4 b0 = *reinterpret_cast<const float4*>(ap + 16 * s);
        float4 b1 = *reinterpret_cast<const float4*>(ap + 16 * s + 4);
        half8 bf;
        bf[0] = (_Float16)b0.x; bf[1] = (_Float16)b0.y;
        bf[2] = (_Float16)b0.z; bf[3] = (_Float16)b0.w;
        bf[4] = (_Float16)b1.x; bf[5] = (_Float16)b1.y;
        bf[6] = (_Float16)b1.z; bf[7] = (_Float16)b1.w;
#pragma unroll
        for (int t = 0; t < 4; ++t) {
            half8 af = *reinterpret_cast<const half8*>(
                WT + (size_t)(l31 + 32 * t) * 128 + 16 * s + 8 * hf);
            acc[t] = __builtin_amdgcn_mfma_f32_32x32x16_f16(af, bf, acc[t], 0, 0, 0);
        }
    }

    if (row < n) {
        _Float16* hp = Hq + (size_t)row * 128;
#pragma unroll
        for (int t = 0; t < 4; ++t)
#pragma unroll
            for (int g = 0; g < 4; ++g) {
                half4v hv;
#pragma unroll
                for (int q = 0; q < 4; ++q) hv[q] = (_Float16)acc[t][4 * g + q];
                *reinterpret_cast<half4v*>(hp + 32 * t + 8 * g + 4 * hf) = hv;
            }
    }
}

// ---------------- Kernel 2: per-node soft medoid ---------------------------
// 256 threads = 4 waves = 4 independent nodes. ZERO LDS; cross-lane via
// shuffles only; idx/tkw rows are wave-uniform -> scalar loads.
__global__ __launch_bounds__(256, 4) void softk(
    const _Float16* __restrict__ hq, const float* __restrict__ bias,
    const float* __restrict__ tkw, const int* __restrict__ idx,
    float* __restrict__ out, int n)
{
    const int wave = threadIdx.x >> 6;
    const int lane = threadIdx.x & 63;
    int node = blockIdx.x * 4 + wave;
    if (node >= n) node = n - 1;            // duplicate compute; benign

    const int l31 = lane & 31;
    const int hf  = lane >> 5;

    const int*   idp = idx + (size_t)node * NK;   // wave-uniform base
    const float* twp = tkw + (size_t)node * NK;   // wave-uniform base

    // per-lane neighbor id / mask / weight for c = l31
    const int vid = idp[l31];
    const int mkc = (vid < 0) ? 1 : 0;
    const int idr = mkc ? 0 : vid;
    const float wc = mkc ? 0.0f : twp[l31];

    // ---- single gather: lane holds row l31, dims [16s + 8hf + j] ----
    const half8* bp = reinterpret_cast<const half8*>(hq + (size_t)idr * DIM);
    half8 frag[8];
#pragma unroll
    for (int s = 0; s < 8; ++s) frag[s] = bp[2 * s + hf];

    // gram = FK @ FK^T (f16 in, fp32 acc)
    f32x16 acc;
#pragma unroll
    for (int i = 0; i < 16; ++i) acc[i] = 0.0f;
#pragma unroll
    for (int s = 0; s < 8; ++s)
        acc = __builtin_amdgcn_mfma_f32_32x32x16_f16(frag[s], frag[s], acc, 0, 0, 0);

    // diagonal -> sq (exact g_cc); C/D: col=l31, rowD=(reg&3)+8(reg>>2)+4hf
    float dval = acc[0];
#pragma unroll
    for (int reg = 0; reg < 16; ++reg) {
        int rD = (reg & 3) + 8 * (reg >> 2) + 4 * hf;
        if (rD == l31) dval = acc[reg];
    }
    const bool own = (((l31 >> 2) & 1) == hf);
    float oth = __shfl_xor(dval, 32, 64);
    float sq  = own ? dval : oth;           // sq[l31] in every lane

    // 9th MFMA: acc += -(sq_m + sq_c)/2  ->  acc = -d2/2.
    // hi/lo f16 split of sq (residual ~sq*2^-22 ~3e-5); /2 and negate exact.
    {
        _Float16 shi = (_Float16)sq;
        _Float16 slo = (_Float16)(sq - (float)shi);
        _Float16 nh  = (_Float16)(-0.5f * (float)shi);
        _Float16 nl  = (_Float16)(-0.5f * (float)slo);
        _Float16 z   = (_Float16)0.0f, one = (_Float16)1.0f;
        half8 aext = {z, z, z, z, z, z, z, z};
        half8 bext = {z, z, z, z, z, z, z, z};
        if (hf == 0) {
            aext[0] = nh;  aext[1] = nl;  aext[2] = one; aext[3] = one;
            bext[0] = one; bext[1] = one; bext[2] = nh;  bext[3] = nl;
        }
        acc = __builtin_amdgcn_mfma_f32_32x32x16_f16(aext, bext, acc, 0, 0, 0);
    }

    // dagg[c=l31] = sum_m w[m] * dist[m][c]; w from scalar loads (no bperm).
    // eps=1e-4 > 3e-5 noise: exact zero for diagonal / duplicate rows.
    float part = 0.0f;
#pragma unroll
    for (int reg = 0; reg < 16; ++reg) {
        const int c = (reg & 3) + 8 * (reg >> 2);
        int   ia = idp[c],     ib = idp[c + 4];          // scalar
        float wa = (ia < 0) ? 0.0f : twp[c];             // scalar
        float wb = (ib < 0) ? 0.0f : twp[c + 4];         // scalar
        float wr = hf ? wb : wa;                         // rD = c + 4hf
        float d2 = fmaxf(-(acc[reg] + acc[reg]), 0.0f);
        float ds = (d2 > 1e-4f) ? __builtin_amdgcn_sqrtf(d2) : 0.0f;
        part = fmaf(wr, ds, part);
    }
    float sA = part + __shfl_xor(part, 32, 64);
    if (mkc || !(sA < 3.4028235e38f)) sA = 3.4028235e38f;

    // softmax over 32 k (duplicated across halves)
    float x  = -sA;
    float mx = x;
#pragma unroll
    for (int o = 16; o > 0; o >>= 1) mx = fmaxf(mx, __shfl_xor(mx, o, 32));
    float e  = __expf(x - mx);
    float se = e;
#pragma unroll
    for (int o = 16; o > 0; o >>= 1) se += __shfl_xor(se, o, 32);
    float r = e * __builtin_amdgcn_rcpf(se);
    r *= wc;
    float sr = r;
#pragma unroll
    for (int o = 16; o > 0; o >>= 1) sr += __shfl_xor(sr, o, 32);
    r = r * __builtin_amdgcn_rcpf(sr);
    if (mkc) r = 0.0f;                      // r_{k=l31} in every lane

    // ---- epilogue: out[d] = sum_k r_k * hq[id_k][d]; 2 dims/lane ----
    // id_k scalar (SGPR base) + lane offset -> fully coalesced dword loads.
    float o0 = 0.0f, o1 = 0.0f;
#pragma unroll
    for (int k = 0; k < NK; ++k) {
        int idk = idp[k];                              // scalar
        idk = idk < 0 ? 0 : idk;                       // (r_k = 0 anyway)
        float rk = __shfl(r, k, 64);
        half2v hv = *reinterpret_cast<const half2v*>(
            hq + (size_t)idk * DIM + 2 * lane);
        o0 = fmaf(rk, (float)hv[0], o0);
        o1 = fmaf(rk, (float)hv[1], o1);
    }
    const int d0 = 2 * lane;
    float2 bv = *reinterpret_cast<const float2*>(bias + d0);
    float2 ov = { o0 + bv.x, o1 + bv.y };
    *reinterpret_cast<float2*>(out + (size_t)node * DIM + d0) = ov;
}

extern "C" void kernel_launch(void* const* d_in, const int* in_sizes, int n_in,
                              void* d_out, int out_size, void* d_ws, size_t ws_size,
                              hipStream_t stream) {
    const float* feat = (const float*)d_in[0];
    const float* W    = (const float*)d_in[1];
    const float* bias = (const float*)d_in[2];
    const float* tkw  = (const float*)d_in[3];
    const int*   idx  = (const int*)d_in[4];
    float* out = (float*)d_out;

    const int n = in_sizes[0] / DIM;                       // 50000
    _Float16* hq = (_Float16*)d_ws;                        // n*128*2 = 12.8 MB
    _Float16* wt = hq + (size_t)n * DIM;                   // 32 KB

    prep<<<64, 256, 0, stream>>>(W, wt);
    gemm128<<<(n + 127) / 128, 256, 0, stream>>>(feat, wt, hq, n);
    softk<<<(n + 3) / 4, 256, 0, stream>>>(hq, bias, tkw, idx, out, n);
}

// Round 6
// 196.846 us; speedup vs baseline: 1.1043x; 1.1043x over previous
//
#include <hip/hip_runtime.h>
#include <math.h>

// SoftKConv, round 6.
// r5 post-mortem: second global gather doubled L2-miss traffic (150->290 MB)
// => memory-bound regression. r6 = single gather (r4) + r5's bpermute kills:
//   - frags staged ONCE to LDS in fragment-order (33-group pad: writes hit
//     the 8-dword/bank floor, epilogue ds_read_b32 2-way-aliased = free)
//   - VALU epilogue: per k one ds_read_b32 (imm offset) + v_readlane r_k
//   - dagg via homogeneous-coordinate 9th MFMA (acc = -d2/2), scalar w
// LDS ~370 cyc/node (vs r4's 932); softk should sit on the gather-traffic
// bound (~150 MB @ ~2.5-3 TB/s).

typedef __attribute__((ext_vector_type(2)))  _Float16 half2v;
typedef __attribute__((ext_vector_type(4)))  _Float16 half4v;
typedef __attribute__((ext_vector_type(8)))  _Float16 half8;
typedef __attribute__((ext_vector_type(16))) float    f32x16;

#define NK   32
#define DIM  128
// LDS layout: half-offset(k,d) = ((d>>3)*33 + k)*8 + (d&7); 16*33*8 = 4224
// halves = 8448 B per node.
#define FKT_SZ 4224

// ---------------- Kernel 0: WT[n][k] = (f16) W[k][n] -----------------------
__global__ __launch_bounds__(256) void prep(const float* __restrict__ W,
                                            _Float16* __restrict__ WT) {
    int t  = blockIdx.x * 256 + threadIdx.x;   // 0..16383
    int nn = t >> 7, k = t & 127;
    WT[t] = (_Float16)W[k * 128 + nn];
}

// ---------------- Kernel 1: h = feat @ W -> f16, MFMA ----------------------
__global__ __launch_bounds__(256) void gemm128(
    const float* __restrict__ A, const _Float16* __restrict__ WT,
    _Float16* __restrict__ Hq, int n)
{
    const int wave = threadIdx.x >> 6;
    const int lane = threadIdx.x & 63;
    const int l31  = lane & 31;
    const int hf   = lane >> 5;

    const int row  = blockIdx.x * 128 + wave * 32 + l31;
    const int rowc = row < n ? row : n - 1;

    f32x16 acc[4];
#pragma unroll
    for (int t = 0; t < 4; ++t)
#pragma unroll
        for (int i = 0; i < 16; ++i) acc[t][i] = 0.0f;

    const float* ap = A + (size_t)rowc * 128 + 8 * hf;
#pragma unroll
    for (int s = 0; s < 8; ++s) {
        float4 b0 = *reinterpret_cast<const float4*>(ap + 16 * s);
        float4 b1 = *reinterpret_cast<const float4*>(ap + 16 * s + 4);
        half8 bf;
        bf[0] = (_Float16)b0.x; bf[1] = (_Float16)b0.y;
        bf[2] = (_Float16)b0.z; bf[3] = (_Float16)b0.w;
        bf[4] = (_Float16)b1.x; bf[5] = (_Float16)b1.y;
        bf[6] = (_Float16)b1.z; bf[7] = (_Float16)b1.w;
#pragma unroll
        for (int t = 0; t < 4; ++t) {
            half8 af = *reinterpret_cast<const half8*>(
                WT + (size_t)(l31 + 32 * t) * 128 + 16 * s + 8 * hf);
            acc[t] = __builtin_amdgcn_mfma_f32_32x32x16_f16(af, bf, acc[t], 0, 0, 0);
        }
    }

    if (row < n) {
        _Float16* hp = Hq + (size_t)row * 128;
#pragma unroll
        for (int t = 0; t < 4; ++t)
#pragma unroll
            for (int g = 0; g < 4; ++g) {
                half4v hv;
#pragma unroll
                for (int q = 0; q < 4; ++q) hv[q] = (_Float16)acc[t][4 * g + q];
                *reinterpret_cast<half4v*>(hp + 32 * t + 8 * g + 4 * hf) = hv;
            }
    }
}

// ---------------- Kernel 2: per-node soft medoid ---------------------------
// 128 threads = 2 waves = 2 independent nodes. Per-wave LDS region -> no
// barriers (LDS ops in-order within a wave).
__global__ __launch_bounds__(128, 4) void softk(
    const _Float16* __restrict__ hq, const float* __restrict__ bias,
    const float* __restrict__ tkw, const int* __restrict__ idx,
    float* __restrict__ out, int n)
{
    __shared__ __align__(16) _Float16 fkT[2][FKT_SZ];   // 16896 B

    const int wave = threadIdx.x >> 6;
    const int lane = threadIdx.x & 63;
    int node = blockIdx.x * 2 + wave;
    if (node >= n) node = n - 1;            // duplicate compute; benign

    const int l31 = lane & 31;
    const int hf  = lane >> 5;

    const int*   idp = idx + (size_t)node * NK;   // wave-uniform base
    const float* twp = tkw + (size_t)node * NK;   // wave-uniform base

    // per-lane neighbor id / mask / weight for c = l31
    const int vid = idp[l31];
    const int mkc = (vid < 0) ? 1 : 0;
    const int idr = mkc ? 0 : vid;
    const float wc = mkc ? 0.0f : twp[l31];

    // ---- single gather: lane holds row l31, dims [16s + 8hf + j] ----
    const half8* bp = reinterpret_cast<const half8*>(hq + (size_t)idr * DIM);
    half8 frag[8];
#pragma unroll
    for (int s = 0; s < 8; ++s) frag[s] = bp[2 * s + hf];

    // ---- stage frags to LDS, fragment-order + 33-pad ----
    // element (row k=l31, dim d=16s+8hf+j) at half-offset ((d>>3)*33+k)*8+j;
    // chunk c = 2s+hf -> write base (c*33 + l31)*8 halves (16-B aligned).
#pragma unroll
    for (int s = 0; s < 8; ++s) {
        int c = 2 * s + hf;
        *reinterpret_cast<half8*>(&fkT[wave][(c * 33 + l31) * 8]) = frag[s];
    }

    // gram = FK @ FK^T (f16 in, fp32 acc)
    f32x16 acc;
#pragma unroll
    for (int i = 0; i < 16; ++i) acc[i] = 0.0f;
#pragma unroll
    for (int s = 0; s < 8; ++s)
        acc = __builtin_amdgcn_mfma_f32_32x32x16_f16(frag[s], frag[s], acc, 0, 0, 0);

    // diagonal -> sq; C/D: col=l31, rowD=(reg&3)+8(reg>>2)+4hf
    float dval = acc[0];
#pragma unroll
    for (int reg = 0; reg < 16; ++reg) {
        int rD = (reg & 3) + 8 * (reg >> 2) + 4 * hf;
        if (rD == l31) dval = acc[reg];
    }
    const bool own = (((l31 >> 2) & 1) == hf);
    float oth = __shfl_xor(dval, 32, 64);
    float sq  = own ? dval : oth;           // sq[l31] in every lane

    // 9th MFMA: acc += -(sq_m + sq_c)/2  ->  acc = -d2/2 (hi/lo f16 split).
    {
        _Float16 shi = (_Float16)sq;
        _Float16 slo = (_Float16)(sq - (float)shi);
        _Float16 nh  = (_Float16)(-0.5f * (float)shi);
        _Float16 nl  = (_Float16)(-0.5f * (float)slo);
        _Float16 z   = (_Float16)0.0f, one = (_Float16)1.0f;
        half8 aext = {z, z, z, z, z, z, z, z};
        half8 bext = {z, z, z, z, z, z, z, z};
        if (hf == 0) {
            aext[0] = nh;  aext[1] = nl;  aext[2] = one; aext[3] = one;
            bext[0] = one; bext[1] = one; bext[2] = nh;  bext[3] = nl;
        }
        acc = __builtin_amdgcn_mfma_f32_32x32x16_f16(aext, bext, acc, 0, 0, 0);
    }

    // dagg[c=l31] = sum_m w[m]*dist[m][c]; w from scalar loads.
    // eps=1e-4 > homog-noise 3e-5: exact zero for diagonal/duplicates.
    float part = 0.0f;
#pragma unroll
    for (int reg = 0; reg < 16; ++reg) {
        const int c = (reg & 3) + 8 * (reg >> 2);
        int   ia = idp[c],     ib = idp[c + 4];          // scalar
        float wa = (ia < 0) ? 0.0f : twp[c];             // scalar
        float wb = (ib < 0) ? 0.0f : twp[c + 4];         // scalar
        float wr = hf ? wb : wa;                         // rD = c + 4hf
        float d2 = fmaxf(-(acc[reg] + acc[reg]), 0.0f);
        float ds = (d2 > 1e-4f) ? __builtin_amdgcn_sqrtf(d2) : 0.0f;
        part = fmaf(wr, ds, part);
    }
    float sA = part + __shfl_xor(part, 32, 64);
    if (mkc || !(sA < 3.4028235e38f)) sA = 3.4028235e38f;

    // softmax over 32 k (duplicated across halves)
    float x  = -sA;
    float mx = x;
#pragma unroll
    for (int o = 16; o > 0; o >>= 1) mx = fmaxf(mx, __shfl_xor(mx, o, 32));
    float e  = __expf(x - mx);
    float se = e;
#pragma unroll
    for (int o = 16; o > 0; o >>= 1) se += __shfl_xor(se, o, 32);
    float r = e * __builtin_amdgcn_rcpf(se);
    r *= wc;
    float sr = r;
#pragma unroll
    for (int o = 16; o > 0; o >>= 1) sr += __shfl_xor(sr, o, 32);
    r = r * __builtin_amdgcn_rcpf(sr);
    if (mkc) r = 0.0f;                      // r_{k=l31} in every lane

    // ---- epilogue: out[d] = sum_k r_k * fk[k][d]; 2 dims/lane from LDS ----
    // lane dims d0=2*lane, d1=d0+1 (same 8-chunk since d0 even). Base VGPR +
    // 16-B imm steps; banks 2-way aliased = free. r_k via v_readlane.
    const int d0 = 2 * lane;
    const _Float16* fb = &fkT[wave][((d0 >> 3) * 33) * 8 + (d0 & 7)];
    float o0 = 0.0f, o1 = 0.0f;
#pragma unroll
    for (int k = 0; k < NK; ++k) {
        union { float f; int i; } rc;
        rc.i = __builtin_amdgcn_readlane(__builtin_bit_cast(int, r), k);
        half2v hv = *reinterpret_cast<const half2v*>(fb + 8 * k);
        o0 = fmaf(rc.f, (float)hv[0], o0);
        o1 = fmaf(rc.f, (float)hv[1], o1);
    }
    float2 bv = *reinterpret_cast<const float2*>(bias + d0);
    float2 ov = { o0 + bv.x, o1 + bv.y };
    *reinterpret_cast<float2*>(out + (size_t)node * DIM + d0) = ov;
}

extern "C" void kernel_launch(void* const* d_in, const int* in_sizes, int n_in,
                              void* d_out, int out_size, void* d_ws, size_t ws_size,
                              hipStream_t stream) {
    const float* feat = (const float*)d_in[0];
    const float* W    = (const float*)d_in[1];
    const float* bias = (const float*)d_in[2];
    const float* tkw  = (const float*)d_in[3];
    const int*   idx  = (const int*)d_in[4];
    float* out = (float*)d_out;

    const int n = in_sizes[0] / DIM;                       // 50000
    _Float16* hq = (_Float16*)d_ws;                        // n*128*2 = 12.8 MB
    _Float16* wt = hq + (size_t)n * DIM;                   // 32 KB

    prep<<<64, 256, 0, stream>>>(W, wt);
    gemm128<<<(n + 127) / 128, 256, 0, stream>>>(feat, wt, hq, n);
    softk<<<(n + 1) / 2, 128, 0, stream>>>(hq, bias, tkw, idx, out, n);
}